// Round 4
// baseline (1107.885 us; speedup 1.0000x reference)
//
#include <hip/hip_runtime.h>

#define N_TOK 16384
#define C_DIM 2048
#define E_NUM 16
#define DE_DIM 128
#define H_DIM 512

typedef __attribute__((ext_vector_type(8))) short bf16x8;
typedef __attribute__((ext_vector_type(4))) float f32x4;

__device__ __forceinline__ unsigned short f2bf(float f) {
    unsigned int u = __float_as_uint(f);
    unsigned int r = u + 0x7fffu + ((u >> 16) & 1u);   // round-to-nearest-even
    return (unsigned short)(r >> 16);
}

// exact-gelu via Abramowitz-Stegun 7.1.26 erf (|err| <= ~2e-7)
__device__ __forceinline__ float gelu_erf(float v) {
    float z  = v * 0.70710678118654752f;
    float az = fabsf(z);
    float t  = __builtin_amdgcn_rcpf(1.0f + 0.3275911f * az);
    float poly = t * (0.254829592f + t * (-0.284496736f + t * (1.421413741f +
                 t * (-1.453152027f + t * 1.061405429f))));
    float ex = __expf(-z * z);
    float er = copysignf(1.0f - poly * ex, z);
    return 0.5f * v * (1.0f + er);
}

// ---------------------------------------------------------------------------
// Kernel A: gate logits (fp64-exact products, fp64 accum) + optional
//           permute/convert x (fp32) -> xp[e][n][128] (bf16).
// block = 256 threads (token nl = t>>3, channel-slice p = t&7), grid = 512
// ---------------------------------------------------------------------------
__global__ __launch_bounds__(256, 2) void moe_gate_permute(
    const float* __restrict__ xg,             // [N][2048] fp32
    const float* __restrict__ gw,             // [16][2048] fp32
    const float* __restrict__ gb,             // [16] fp32
    unsigned short* __restrict__ xp,          // [16][N][128] bf16 (if do_permute)
    float* __restrict__ gwf,                  // [N][16] float 0/1
    int do_permute)
{
    __shared__ float gws[16 * 256];           // gate_w chunk, 16 KiB
    __shared__ unsigned short xs[32 * 264];   // 32 tokens x 256-ch chunk bf16 (+8 pad)

    const int t  = threadIdx.x;
    const int n0 = blockIdx.x * 32;
    const int nl = t >> 3;     // token-local 0..31
    const int p  = t & 7;      // channel-slice 0..7

    double dacc[16];
#pragma unroll
    for (int e = 0; e < 16; ++e) dacc[e] = 0.0;

    for (int cc = 0; cc < 8; ++cc) {
        __syncthreads();   // protect gws/xs from previous iteration readers
        // stage gate_w chunk [16][256] into LDS (coalesced float4)
#pragma unroll
        for (int ii = 0; ii < 4; ++ii) {
            int fi = ii * 1024 + t * 4;
            int e = fi >> 8, cl = fi & 255;
            *reinterpret_cast<float4*>(&gws[e * 256 + cl]) =
                *reinterpret_cast<const float4*>(gw + (size_t)e * 2048 + cc * 256 + cl);
        }
        __syncthreads();
#pragma unroll
        for (int i = 0; i < 4; ++i) {
            const int cl = p * 8 + i * 64;          // channel within 256-chunk
            const float* xr = xg + (size_t)(n0 + nl) * 2048 + cc * 256 + cl;
            float4 xa = *reinterpret_cast<const float4*>(xr);
            float4 xb = *reinterpret_cast<const float4*>(xr + 4);
            double xd0 = xa.x, xd1 = xa.y, xd2 = xa.z, xd3 = xa.w;
            double xd4 = xb.x, xd5 = xb.y, xd6 = xb.z, xd7 = xb.w;
#pragma unroll
            for (int e = 0; e < 16; ++e) {
                float4 ga = *reinterpret_cast<const float4*>(&gws[e * 256 + cl]);
                float4 gv = *reinterpret_cast<const float4*>(&gws[e * 256 + cl + 4]);
                double s = dacc[e];
                s = fma(xd0, (double)ga.x, s);
                s = fma(xd1, (double)ga.y, s);
                s = fma(xd2, (double)ga.z, s);
                s = fma(xd3, (double)ga.w, s);
                s = fma(xd4, (double)gv.x, s);
                s = fma(xd5, (double)gv.y, s);
                s = fma(xd6, (double)gv.z, s);
                s = fma(xd7, (double)gv.w, s);
                dacc[e] = s;
            }
            if (do_permute) {
                unsigned int w0 = (unsigned int)f2bf(xa.x) | ((unsigned int)f2bf(xa.y) << 16);
                unsigned int w1 = (unsigned int)f2bf(xa.z) | ((unsigned int)f2bf(xa.w) << 16);
                unsigned int w2 = (unsigned int)f2bf(xb.x) | ((unsigned int)f2bf(xb.y) << 16);
                unsigned int w3 = (unsigned int)f2bf(xb.z) | ((unsigned int)f2bf(xb.w) << 16);
                *reinterpret_cast<uint4*>(&xs[nl * 264 + cl]) = make_uint4(w0, w1, w2, w3);
            }
        }
        if (do_permute) {
            __syncthreads();
            // transposed write-out: rows (n,e), d-range cc*16..+16
#pragma unroll
            for (int rr = 0; rr < 2; ++rr) {
                const int rid = t + rr * 256;
                const int rn  = rid >> 4;
                const int re  = rid & 15;
                unsigned int w[8];
#pragma unroll
                for (int k = 0; k < 8; ++k) {
                    unsigned int lo = xs[rn * 264 + (2 * k) * 16 + re];
                    unsigned int hi = xs[rn * 264 + (2 * k + 1) * 16 + re];
                    w[k] = lo | (hi << 16);
                }
                size_t off = ((size_t)re * N_TOK + (n0 + rn)) * 128 + cc * 16;
                uint4* dst = reinterpret_cast<uint4*>(xp + off);
                dst[0] = make_uint4(w[0], w[1], w[2], w[3]);
                dst[1] = make_uint4(w[4], w[5], w[6], w[7]);
            }
        }
    }
    // reduce over the 8 p-lanes (contiguous lane bits 0..2) via xor-shuffle
#pragma unroll
    for (int e = 0; e < 16; ++e) {
        double v = dacc[e];
        v += __shfl_xor(v, 1);
        v += __shfl_xor(v, 2);
        v += __shfl_xor(v, 4);
        dacc[e] = v;   // all 8 p-lanes now hold the full sum for token nl
    }
    const int e0 = 2 * p;
    float g0 = (dacc[e0]     + (double)gb[e0]     > 0.0) ? 1.0f : 0.0f;
    float g1 = (dacc[e0 + 1] + (double)gb[e0 + 1] > 0.0) ? 1.0f : 0.0f;
    float2* gout = reinterpret_cast<float2*>(gwf + (size_t)(n0 + nl) * 16 + e0);
    *gout = make_float2(g0, g1);
}

// ---------------------------------------------------------------------------
// Kernel B: per-expert MLP, bf16 MFMA 16x16x32; weights fp32 -> bf16 at staging
// grid = 2048 (e = bx>>7, token-block = bx&127), 256 threads = 4 waves,
// wave = 32 tokens x 128 out-channels; H chunked by 64. OUTPUT: fp32.
// use_xp=0: gather x directly (strided) instead of reading permuted xp.
// ---------------------------------------------------------------------------
__global__ __launch_bounds__(256, 2) void moe_expert_mlp(
    const float* __restrict__ xg,             // [N][2048] fp32 (fallback path)
    const unsigned short* __restrict__ xp,    // [16][N][128] bf16
    const float* __restrict__ fcw,            // [16][512][128] fp32
    const float* __restrict__ fcb,            // [16][512] fp32
    const float* __restrict__ pjw,            // [16][128][512] fp32
    const float* __restrict__ pjb,            // [16][128] fp32
    const float* __restrict__ gwf,            // [N][16]
    float* __restrict__ y,                    // [N][2048] fp32
    int use_xp)
{
    __shared__ unsigned short W1s[64 * 136];       // [hh_local][d], pad->136
    __shared__ unsigned short W2s[128 * 72];       // [d][hh_local], pad->72
    __shared__ unsigned short Hs[4 * 32 * 72];     // per-wave [tok_local][hh_local]

    const int t    = threadIdx.x;
    const int wid  = t >> 6;
    const int lane = t & 63;
    const int q    = lane >> 4;
    const int m    = lane & 15;
    const int e    = blockIdx.x >> 7;
    const int tb   = blockIdx.x & 127;
    const int n0   = tb * 128 + wid * 32;

    // A fragments for this wave's 32 tokens: A[m=lane&15][k=q*8+j]
    bf16x8 a1[2][4];
    if (use_xp) {
#pragma unroll
        for (int tm = 0; tm < 2; ++tm)
#pragma unroll
            for (int kk = 0; kk < 4; ++kk)
                a1[tm][kk] = *reinterpret_cast<const bf16x8*>(
                    xp + ((size_t)e * N_TOK + n0 + tm * 16 + m) * 128 + kk * 32 + q * 8);
    } else {
#pragma unroll
        for (int tm = 0; tm < 2; ++tm)
#pragma unroll
            for (int kk = 0; kk < 4; ++kk) {
                const float* base = xg + (size_t)(n0 + tm * 16 + m) * 2048
                                  + (kk * 32 + q * 8) * 16 + e;
                union { unsigned short u[8]; bf16x8 v; } pk;
#pragma unroll
                for (int j = 0; j < 8; ++j) pk.u[j] = f2bf(base[j * 16]);
                a1[tm][kk] = pk.v;
            }
    }

    f32x4 oacc[2][8];
#pragma unroll
    for (int tm = 0; tm < 2; ++tm)
#pragma unroll
        for (int tn = 0; tn < 8; ++tn) oacc[tm][tn] = (f32x4){0.f, 0.f, 0.f, 0.f};

    unsigned short* HsW = &Hs[wid * 32 * 72];

    for (int hc = 0; hc < 8; ++hc) {
        __syncthreads();   // previous chunk's weight readers done
        // stage W1 chunk: fc_w[e][hc*64 .. +64][0..128], fp32 -> bf16
#pragma unroll
        for (int it = 0; it < 4; ++it) {
            int idx = it * 256 + t;
            int hh = idx >> 4, ds = (idx & 15) * 8;
            const float* src = fcw + ((size_t)e * 512 + hc * 64 + hh) * 128 + ds;
            float4 va = *reinterpret_cast<const float4*>(src);
            float4 vb = *reinterpret_cast<const float4*>(src + 4);
            unsigned int w0 = (unsigned int)f2bf(va.x) | ((unsigned int)f2bf(va.y) << 16);
            unsigned int w1 = (unsigned int)f2bf(va.z) | ((unsigned int)f2bf(va.w) << 16);
            unsigned int w2 = (unsigned int)f2bf(vb.x) | ((unsigned int)f2bf(vb.y) << 16);
            unsigned int w3 = (unsigned int)f2bf(vb.z) | ((unsigned int)f2bf(vb.w) << 16);
            *reinterpret_cast<uint4*>(&W1s[hh * 136 + ds]) = make_uint4(w0, w1, w2, w3);
        }
        // stage W2 chunk: proj_w[e][0..128][hc*64 .. +64], fp32 -> bf16
#pragma unroll
        for (int it = 0; it < 4; ++it) {
            int idx = it * 256 + t;
            int d = idx >> 3, cs = (idx & 7) * 8;
            const float* src = pjw + ((size_t)e * 128 + d) * 512 + hc * 64 + cs;
            float4 va = *reinterpret_cast<const float4*>(src);
            float4 vb = *reinterpret_cast<const float4*>(src + 4);
            unsigned int w0 = (unsigned int)f2bf(va.x) | ((unsigned int)f2bf(va.y) << 16);
            unsigned int w1 = (unsigned int)f2bf(va.z) | ((unsigned int)f2bf(va.w) << 16);
            unsigned int w2 = (unsigned int)f2bf(vb.x) | ((unsigned int)f2bf(vb.y) << 16);
            unsigned int w3 = (unsigned int)f2bf(vb.z) | ((unsigned int)f2bf(vb.w) << 16);
            *reinterpret_cast<uint4*>(&W2s[d * 72 + cs]) = make_uint4(w0, w1, w2, w3);
        }
        __syncthreads();

        // GEMM1: H1[32 x 64] = Xe[32 x 128] * W1[128 x 64]
        f32x4 h1[2][4];
#pragma unroll
        for (int tm = 0; tm < 2; ++tm)
#pragma unroll
            for (int tn = 0; tn < 4; ++tn) h1[tm][tn] = (f32x4){0.f, 0.f, 0.f, 0.f};
#pragma unroll
        for (int kk = 0; kk < 4; ++kk) {
#pragma unroll
            for (int tn = 0; tn < 4; ++tn) {
                bf16x8 b = *reinterpret_cast<const bf16x8*>(
                    &W1s[(tn * 16 + m) * 136 + kk * 32 + q * 8]);
                h1[0][tn] = __builtin_amdgcn_mfma_f32_16x16x32_bf16(a1[0][kk], b, h1[0][tn], 0, 0, 0);
                h1[1][tn] = __builtin_amdgcn_mfma_f32_16x16x32_bf16(a1[1][kk], b, h1[1][tn], 0, 0, 0);
            }
        }
        // bias + gelu -> Hs (C/D layout: row = tm*16+q*4+r, col = tn*16+m)
#pragma unroll
        for (int tn = 0; tn < 4; ++tn) {
            float bias = fcb[e * 512 + hc * 64 + tn * 16 + m];
#pragma unroll
            for (int tm = 0; tm < 2; ++tm)
#pragma unroll
                for (int r = 0; r < 4; ++r) {
                    float g = gelu_erf(h1[tm][tn][r] + bias);
                    HsW[(tm * 16 + q * 4 + r) * 72 + tn * 16 + m] = f2bf(g);
                }
        }
        __asm__ volatile("" ::: "memory");  // order Hs writes before A2 reads

        // GEMM2: Oacc[32 x 128] += gelu(H1)[32 x 64] * W2[64 x 128]
#pragma unroll
        for (int kk2 = 0; kk2 < 2; ++kk2) {
            bf16x8 a2_0 = *reinterpret_cast<const bf16x8*>(&HsW[(m) * 72 + kk2 * 32 + q * 8]);
            bf16x8 a2_1 = *reinterpret_cast<const bf16x8*>(&HsW[(16 + m) * 72 + kk2 * 32 + q * 8]);
#pragma unroll
            for (int tn2 = 0; tn2 < 8; ++tn2) {
                bf16x8 b2 = *reinterpret_cast<const bf16x8*>(
                    &W2s[(tn2 * 16 + m) * 72 + kk2 * 32 + q * 8]);
                oacc[0][tn2] = __builtin_amdgcn_mfma_f32_16x16x32_bf16(a2_0, b2, oacc[0][tn2], 0, 0, 0);
                oacc[1][tn2] = __builtin_amdgcn_mfma_f32_16x16x32_bf16(a2_1, b2, oacc[1][tn2], 0, 0, 0);
            }
        }
    }

    // epilogue: (acc + proj_b) * gate, store FP32 at y[n][e*128 + d]
    float gwv[2][4];
#pragma unroll
    for (int tm = 0; tm < 2; ++tm)
#pragma unroll
        for (int r = 0; r < 4; ++r)
            gwv[tm][r] = gwf[(size_t)(n0 + tm * 16 + q * 4 + r) * 16 + e];
#pragma unroll
    for (int tn2 = 0; tn2 < 8; ++tn2) {
        float pb = pjb[e * 128 + tn2 * 16 + m];
#pragma unroll
        for (int tm = 0; tm < 2; ++tm)
#pragma unroll
            for (int r = 0; r < 4; ++r) {
                float v = (oacc[tm][tn2][r] + pb) * gwv[tm][r];
                y[(size_t)(n0 + tm * 16 + q * 4 + r) * 2048 + e * 128 + tn2 * 16 + m] = v;
            }
    }
}

extern "C" void kernel_launch(void* const* d_in, const int* in_sizes, int n_in,
                              void* d_out, int out_size, void* d_ws, size_t ws_size,
                              hipStream_t stream) {
    const float* x      = (const float*)d_in[0];
    const float* gate_w = (const float*)d_in[1];
    const float* gate_b = (const float*)d_in[2];
    const float* fc_w   = (const float*)d_in[3];
    const float* fc_b   = (const float*)d_in[4];
    const float* proj_w = (const float*)d_in[5];
    const float* proj_b = (const float*)d_in[6];
    float* y            = (float*)d_out;

    // ws layout: gwf (1 MiB) at offset 0; xp (64 MiB) after, only if it fits.
    const size_t gwf_bytes = (size_t)N_TOK * E_NUM * 4;                 // 1 MiB
    const size_t xp_bytes  = (size_t)E_NUM * N_TOK * DE_DIM * 2;        // 64 MiB
    float* gwf = (float*)d_ws;
    unsigned short* xp = (unsigned short*)((char*)d_ws + gwf_bytes);
    const int use_xp = (ws_size >= gwf_bytes + xp_bytes) ? 1 : 0;

    moe_gate_permute<<<dim3(N_TOK / 32), dim3(256), 0, stream>>>(
        x, gate_w, gate_b, xp, gwf, use_xp);
    moe_expert_mlp<<<dim3(E_NUM * (N_TOK / 128)), dim3(256), 0, stream>>>(
        x, xp, fc_w, fc_b, proj_w, proj_b, gwf, y, use_xp);
}